// Round 9
// baseline (306.142 us; speedup 1.0000x reference)
//
#include <hip/hip_runtime.h>

typedef float f32x4 __attribute__((ext_vector_type(4)));

#define LOG2E 1.4426950408889634f
#define ALPHA 0.2f
#define NB    1024
#define NCH   16
#define BRANGE 24.0f
#define BSCALE (1024.0f / 24.0f)

__device__ __forceinline__ float fexp2(float v) {
#if __has_builtin(__builtin_amdgcn_exp2f)
  return __builtin_amdgcn_exp2f(v);
#else
  return exp2f(v);
#endif
}

// monotone bucket map on v <= 0 (shifted-f2 domain); exact compares fix boundaries
__device__ __forceinline__ int bucketof(float v) {
  int c = (int)((v + BRANGE) * BSCALE);
  return min(max(c, 0), NB - 1);
}

// ---------------- kernel 1: f1/f2 rows, pre-scaled by log2(e) (proven) ----------------
__global__ __launch_bounds__(256) void fkern(
    const float* __restrict__ emb, const float* __restrict__ W,
    const float* __restrict__ a, float* __restrict__ f1, float* __restrict__ f2)
{
  __shared__ float Ws[64 * 65];
  __shared__ float w1s[64], w2s[64];
  const int t = threadIdx.x;
#pragma unroll
  for (int i = 0; i < 16; ++i) {
    const int idx = i * 256 + t;
    Ws[(idx >> 6) * 65 + (idx & 63)] = W[idx];
  }
  __syncthreads();
  if (t < 128) {
    const int d = t & 63;
    const float* av = a + (t >> 6) * 64;
    float s = 0.f;
#pragma unroll
    for (int h = 0; h < 64; ++h) s = fmaf(Ws[d * 65 + h], av[h], s);
    if (t < 64) w1s[d] = s; else w2s[d] = s;
  }
  __syncthreads();
  const int R = blockIdx.x * 64 + (t >> 2);
  const int q = t & 3;
  const f32x4* er = (const f32x4*)(emb + (size_t)R * 64 + q * 16);
  float s1 = 0.f, s2 = 0.f;
#pragma unroll
  for (int r = 0; r < 4; ++r) {
    f32x4 v = er[r];
#pragma unroll
    for (int c = 0; c < 4; ++c) {
      s1 = fmaf(v[c], w1s[q * 16 + r * 4 + c], s1);
      s2 = fmaf(v[c], w2s[q * 16 + r * 4 + c], s2);
    }
  }
  s1 += __shfl_xor(s1, 1); s1 += __shfl_xor(s1, 2);
  s2 += __shfl_xor(s2, 1); s2 += __shfl_xor(s2, 2);
  if (q == 0) { f1[R] = s1 * LOG2E; f2[R] = s2 * LOG2E; }
}

// ---------------- kernel 2: per-batch bucket sort, row ranks, Z ----------------
__global__ __launch_bounds__(1024) void rankkern(
    const float* __restrict__ f1g, const float* __restrict__ f2g,
    float* __restrict__ f2s_w, float* __restrict__ e1s_w, float* __restrict__ e2s_w,
    float* __restrict__ GA_w, float* __restrict__ GB_w, float* __restrict__ TAU_w,
    int* __restrict__ pi_w, int* __restrict__ rpi_w,
    int* __restrict__ jb_w, int* __restrict__ rb_w)
{
  __shared__ float sA[1024], sB[1024], sC[1024];
  __shared__ int iS[1024], iH[1024], iB[1025], iR[1025];
  const int t = threadIdx.x;
  const int b = blockIdx.x;
  const int boff = b * 1024;

  const float f2v = f2g[boff + t];
  // block max of f2
  sB[t] = f2v; __syncthreads();
  for (int s = 512; s > 0; s >>= 1) {
    if (t < s) sB[t] = fmaxf(sB[t], sB[t + s]);
    __syncthreads();
  }
  const float mf2 = sB[0];
  __syncthreads();

  const float v = f2v - mf2;            // <= 0
  const int c = bucketof(v);
  // histogram of j-buckets
  iH[t] = 0; __syncthreads();
  atomicAdd(&iH[c], 1); __syncthreads();
  // inclusive scan (Hillis-Steele) on copy
  iS[t] = iH[t]; __syncthreads();
  for (int off = 1; off < 1024; off <<= 1) {
    int val = iS[t];
    int add = (t >= off) ? iS[t - off] : 0;
    __syncthreads();
    iS[t] = val + add;
    __syncthreads();
  }
  iB[t] = iS[t] - iH[t];
  jb_w[b * 1025 + t] = iB[t];
  if (t == 0) { iB[1024] = 1024; jb_w[b * 1025 + 1024] = 1024; }
  __syncthreads();
  // counting-sort scatter of j
  iH[t] = 0; __syncthreads();
  {
    int rank = iB[c] + atomicAdd(&iH[c], 1);
    sA[rank] = v;
    pi_w[boff + rank] = t;
  }
  __syncthreads();
  // sorted tables + prefix scans of e1, e2
  const float vs = sA[t];
  const float e1v = fexp2(vs);
  const float e2v = fexp2(ALPHA * vs);
  f2s_w[boff + t] = vs;
  e1s_w[boff + t] = e1v;
  e2s_w[boff + t] = e2v;
  sB[t] = e1v; sC[t] = e2v;
  __syncthreads();
  for (int off = 1; off < 1024; off <<= 1) {
    float v1 = sB[t], v2 = sC[t];
    float a1 = (t >= off) ? sB[t - off] : 0.f;
    float a2 = (t >= off) ? sC[t - off] : 0.f;
    __syncthreads();
    sB[t] = v1 + a1; sC[t] = v2 + a2;
    __syncthreads();
  }
  const float TE1 = sB[1023];
  // rows
  const float F1 = f1g[boff + t];
  const float u = F1 + mf2;
  const float tau = -u;                 // condition: f2s_j < tau  <=> B-branch
  const float mL = fmaxf(u, ALPHA * u);
  const float CA = fexp2(u - mL);
  const float CB = fexp2(ALPHA * u - mL);
  const int cr = bucketof(tau);
  // counting sort of rows by bucket
  iH[t] = 0; __syncthreads();
  atomicAdd(&iH[cr], 1); __syncthreads();
  iS[t] = iH[t]; __syncthreads();
  for (int off = 1; off < 1024; off <<= 1) {
    int val = iS[t];
    int add = (t >= off) ? iS[t - off] : 0;
    __syncthreads();
    iS[t] = val + add;
    __syncthreads();
  }
  iR[t] = iS[t] - iH[t];
  rb_w[b * 1025 + t] = iR[t];
  if (t == 0) { iR[1024] = 1024; rb_w[b * 1025 + 1024] = 1024; }
  __syncthreads();
  iH[t] = 0; __syncthreads();
  {
    int rrank = iR[cr] + atomicAdd(&iH[cr], 1);
    rpi_w[boff + rrank] = t;
  }
  // Z and folded constants
  const int lo = iB[cr], hi = iB[cr + 1];
  const float pre1 = lo ? sB[lo - 1] : 0.f;
  const float pre2 = lo ? sC[lo - 1] : 0.f;
  float sp1 = 0.f, sp2 = 0.f;
  for (int r = lo; r < hi; ++r) {
    float vv = sA[r];
    if (vv < tau) { sp1 += fexp2(vv); sp2 += fexp2(ALPHA * vv); }
  }
  const float SAs = TE1 - pre1 - sp1;
  const float SBs = pre2 + sp2;
  const float Z = CA * SAs + CB * SBs;
  GA_w[boff + t] = CA / Z;
  GB_w[boff + t] = CB / Z;
  TAU_w[boff + t] = tau;
}

// ---------------- kernel 3a: chunk vector sums V1/V2 ----------------
__global__ __launch_bounds__(256) void chunkkern(
    const float* __restrict__ x,
    const float* __restrict__ e1s_w, const float* __restrict__ e2s_w,
    const int* __restrict__ pi_w, const int* __restrict__ jb_w,
    float* __restrict__ V1_w, float* __restrict__ V2_w)
{
  __shared__ float r1[4][64], r2[4][64];
  const int t = threadIdx.x;
  const int d = t & 63, w = t >> 6;
  const int id = blockIdx.x;
  const int c = id & (NCH - 1);
  const int h = (id >> 4) & 1;
  const int b = id >> 5;
  const int boff = b * 1024;
  const int lo = jb_w[b * 1025 + c * 64];
  const int hi = jb_w[b * 1025 + (c + 1) * 64];
  const float* xb = x + (size_t)(b + 32 * h) * 65536;
  float a1 = 0.f, a2 = 0.f;
  for (int r = lo + w; r < hi; r += 4) {
    const int j = pi_w[boff + r];
    const float xv = xb[j * 64 + d];
    a1 = fmaf(e1s_w[boff + r], xv, a1);
    a2 = fmaf(e2s_w[boff + r], xv, a2);
  }
  r1[w][d] = a1; r2[w][d] = a2;
  __syncthreads();
  if (w == 0) {
    V1_w[id * 64 + d] = r1[0][d] + r1[1][d] + r1[2][d] + r1[3][d];
    V2_w[id * 64 + d] = r2[0][d] + r2[1][d] + r2[2][d] + r2[3][d];
  }
}

// ---------------- kernel 3b: per-chunk sweep + row emission ----------------
__global__ __launch_bounds__(64) void sweepkern(
    const float* __restrict__ x,
    const float* __restrict__ f2s_w, const float* __restrict__ e1s_w,
    const float* __restrict__ e2s_w,
    const float* __restrict__ GA_w, const float* __restrict__ GB_w,
    const float* __restrict__ TAU_w,
    const int* __restrict__ pi_w, const int* __restrict__ rpi_w,
    const int* __restrict__ jb_w, const int* __restrict__ rb_w,
    const float* __restrict__ V1_w, const float* __restrict__ V2_w,
    float* __restrict__ out)
{
  const int d = threadIdx.x;
  const int id = blockIdx.x;
  const int c = id & (NCH - 1);
  const int h = (id >> 4) & 1;
  const int b = id >> 5;
  const int boff = b * 1024;
  const int vbase = (b * 2 + h) * (NCH * 64);
  float base1 = 0.f, base2 = 0.f, T1 = 0.f;
  for (int cc = 0; cc < NCH; ++cc) {
    float v1 = V1_w[vbase + cc * 64 + d];
    float v2 = V2_w[vbase + cc * 64 + d];
    T1 += v1;
    if (cc < c) { base1 += v1; base2 += v2; }
  }
  float run1 = base1, run2 = base2;
  const float* xb = x + (size_t)(b + 32 * h) * 65536;
  float* ob = out + (size_t)(h * 32 + b) * 65536;
  for (int cb = c * 64; cb < (c + 1) * 64; ++cb) {
    const int jlo = jb_w[b * 1025 + cb], jhi = jb_w[b * 1025 + cb + 1];
    const int rlo = rb_w[b * 1025 + cb], rhi = rb_w[b * 1025 + cb + 1];
    for (int ri = rlo; ri < rhi; ++ri) {
      const int i = rpi_w[boff + ri];
      const float ga = GA_w[boff + i], gb = GB_w[boff + i], ta = TAU_w[boff + i];
      float p1 = 0.f, p2 = 0.f;
      for (int r = jlo; r < jhi; ++r) {
        if (f2s_w[boff + r] < ta) {
          const float xv = xb[pi_w[boff + r] * 64 + d];
          p1 = fmaf(e1s_w[boff + r], xv, p1);
          p2 = fmaf(e2s_w[boff + r], xv, p2);
        }
      }
      ob[(size_t)i * 64 + d] = ga * (T1 - run1 - p1) + gb * (run2 + p2);
    }
    for (int r = jlo; r < jhi; ++r) {
      const float xv = xb[pi_w[boff + r] * 64 + d];
      run1 = fmaf(e1s_w[boff + r], xv, run1);
      run2 = fmaf(e2s_w[boff + r], xv, run2);
    }
  }
}

extern "C" void kernel_launch(void* const* d_in, const int* in_sizes, int n_in,
                              void* d_out, int out_size, void* d_ws, size_t ws_size,
                              hipStream_t stream) {
  const float* emb = (const float*)d_in[0];
  const float* x   = (const float*)d_in[1];
  const float* W   = (const float*)d_in[2];
  const float* a   = (const float*)d_in[3];
  float* wsf = (float*)d_ws;
  float* f1  = wsf;            // 32768 each
  float* f2  = wsf + 32768;
  float* f2s = wsf + 65536;
  float* e1s = wsf + 98304;
  float* e2s = wsf + 131072;
  float* GA  = wsf + 163840;
  float* GB  = wsf + 196608;
  float* TAU = wsf + 229376;
  float* V1  = wsf + 262144;   // 65536
  float* V2  = wsf + 327680;   // 65536
  int* pi  = (int*)(wsf + 393216);   // 32768
  int* rpi = (int*)(wsf + 425984);   // 32768
  int* jb  = (int*)(wsf + 458752);   // 32*1025
  int* rb  = (int*)(wsf + 491552);   // 32*1025
  fkern<<<512, 256, 0, stream>>>(emb, W, a, f1, f2);
  rankkern<<<32, 1024, 0, stream>>>(f1, f2, f2s, e1s, e2s, GA, GB, TAU, pi, rpi, jb, rb);
  chunkkern<<<32 * 2 * NCH, 256, 0, stream>>>(x, e1s, e2s, pi, jb, V1, V2);
  sweepkern<<<32 * 2 * NCH, 64, 0, stream>>>(x, f2s, e1s, e2s, GA, GB, TAU, pi, rpi, jb, rb, V1, V2, (float*)d_out);
}

// Round 10
// 62.865 us; speedup vs baseline: 4.8698x; 4.8698x over previous
//
#include <hip/hip_runtime.h>

typedef float f32x4 __attribute__((ext_vector_type(4)));

#define LOG2E 1.4426950408889634f
#define ALPHA 0.2f

__device__ __forceinline__ float fexp2(float v) {
#if __has_builtin(__builtin_amdgcn_exp2f)
  return __builtin_amdgcn_exp2f(v);
#else
  return exp2f(v);
#endif
}

// ---------------- kernel 1: f1/f2 rows, pre-scaled by log2(e) (proven) ----------------
__global__ __launch_bounds__(256) void fkern(
    const float* __restrict__ emb, const float* __restrict__ W,
    const float* __restrict__ a, float* __restrict__ f1, float* __restrict__ f2)
{
  __shared__ float Ws[64 * 65];
  __shared__ float w1s[64], w2s[64];
  const int t = threadIdx.x;
#pragma unroll
  for (int i = 0; i < 16; ++i) {
    const int idx = i * 256 + t;
    Ws[(idx >> 6) * 65 + (idx & 63)] = W[idx];
  }
  __syncthreads();
  if (t < 128) {
    const int d = t & 63;
    const float* av = a + (t >> 6) * 64;
    float s = 0.f;
#pragma unroll
    for (int h = 0; h < 64; ++h) s = fmaf(Ws[d * 65 + h], av[h], s);
    if (t < 64) w1s[d] = s; else w2s[d] = s;
  }
  __syncthreads();
  const int R = blockIdx.x * 64 + (t >> 2);
  const int q = t & 3;
  const f32x4* er = (const f32x4*)(emb + (size_t)R * 64 + q * 16);
  float s1 = 0.f, s2 = 0.f;
#pragma unroll
  for (int r = 0; r < 4; ++r) {
    f32x4 v = er[r];
#pragma unroll
    for (int c = 0; c < 4; ++c) {
      s1 = fmaf(v[c], w1s[q * 16 + r * 4 + c], s1);
      s2 = fmaf(v[c], w2s[q * 16 + r * 4 + c], s2);
    }
  }
  s1 += __shfl_xor(s1, 1); s1 += __shfl_xor(s1, 2);
  s2 += __shfl_xor(s2, 1); s2 += __shfl_xor(s2, 2);
  if (q == 0) { f1[R] = s1 * LOG2E; f2[R] = s2 * LOG2E; }
}

// ---------------- kernel 2: exact sort + ranks + Z (per batch) ----------------
__global__ __launch_bounds__(1024) void rankkern(
    const float* __restrict__ f1g, const float* __restrict__ f2g,
    float* __restrict__ e1s_w, float* __restrict__ e2s_w,
    float* __restrict__ GA_w, float* __restrict__ GB_w, int* __restrict__ trk_w,
    int* __restrict__ pi_w, int* __restrict__ rpi_w, int* __restrict__ rc_w)
{
  __shared__ unsigned long long skey[1024];
  __shared__ float sA[1024], sB[1024], sC[1024];
  __shared__ int hist[16], hbase[17], cnt[16];
  const int t = threadIdx.x;
  const int b = blockIdx.x;
  const int boff = b << 10;

  const float f2v = f2g[boff + t];
  sB[t] = f2v; __syncthreads();
  for (int s = 512; s > 0; s >>= 1) {
    if (t < s) sB[t] = fmaxf(sB[t], sB[t + s]);
    __syncthreads();
  }
  const float mf2 = sB[0];
  __syncthreads();

  const float v = f2v - mf2;            // <= 0
  const unsigned kb = ~__builtin_bit_cast(unsigned, v);   // monotone key (neg & +0)
  skey[t] = ((unsigned long long)kb << 32) | (unsigned)t;
  __syncthreads();
  // bitonic sort ascending (value ascending)
  for (int k = 2; k <= 1024; k <<= 1) {
    for (int j = k >> 1; j > 0; j >>= 1) {
      const int ixj = t ^ j;
      if (ixj > t) {
        unsigned long long a0 = skey[t], c0 = skey[ixj];
        const bool up = ((t & k) == 0);
        if ((a0 > c0) == up) { skey[t] = c0; skey[ixj] = a0; }
      }
      __syncthreads();
    }
  }
  const unsigned long long me = skey[t];
  pi_w[boff + t] = (int)(me & 0xFFFFFFFFu);
  const float vs = __builtin_bit_cast(float, ~(unsigned)(me >> 32));
  const float e1v = fexp2(vs), e2v = fexp2(ALPHA * vs);
  e1s_w[boff + t] = e1v; e2s_w[boff + t] = e2v;
  sA[t] = vs; sB[t] = e1v; sC[t] = e2v;
  __syncthreads();
  // inclusive scalar prefix sums of e1, e2 (Hillis-Steele)
  for (int off = 1; off < 1024; off <<= 1) {
    float v1 = sB[t], v2 = sC[t];
    float a1 = (t >= off) ? sB[t - off] : 0.f;
    float a2 = (t >= off) ? sC[t - off] : 0.f;
    __syncthreads();
    sB[t] = v1 + a1; sC[t] = v2 + a2;
    __syncthreads();
  }
  const float TE1 = sB[1023];
  // rows: exact rank via lower_bound, Z from scalar prefixes
  const float u   = f1g[boff + t] + mf2;
  const float tau = -u;                 // B-branch: vs < tau
  const float mL  = fmaxf(u, ALPHA * u);
  const float CA  = fexp2(u - mL);
  const float CB  = fexp2(fmaf(ALPHA, u, -mL));
  int lo = 0, hi = 1024;
  while (lo < hi) { const int mid = (lo + hi) >> 1; if (sA[mid] < tau) lo = mid + 1; else hi = mid; }
  const int ti = lo;                    // count of values < tau
  const float pre1 = ti ? sB[ti - 1] : 0.f;
  const float pre2 = ti ? sC[ti - 1] : 0.f;
  const float Z = CA * (TE1 - pre1) + CB * pre2;
  GA_w[boff + t] = CA / Z;
  GB_w[boff + t] = CB / Z;
  trk_w[boff + t] = ti;
  // counting-sort rows by chunk ci = min(ti>>6, 15)
  const int ci = min(ti >> 6, 15);
  if (t < 16) { hist[t] = 0; cnt[t] = 0; }
  __syncthreads();
  atomicAdd(&hist[ci], 1);
  __syncthreads();
  if (t == 0) {
    int s = 0;
#pragma unroll
    for (int c2 = 0; c2 < 16; ++c2) { hbase[c2] = s; rc_w[b * 17 + c2] = s; s += hist[c2]; }
    rc_w[b * 17 + 16] = s;
  }
  __syncthreads();
  const int rr = hbase[ci] + atomicAdd(&cnt[ci], 1);
  rpi_w[boff + rr] = t;
}

// ---------------- kernel 3a: chunk vector sums (fixed 64-rank chunks) ----------------
__global__ __launch_bounds__(256) void chunkkern(
    const float* __restrict__ x,
    const float* __restrict__ e1s_w, const float* __restrict__ e2s_w,
    const int* __restrict__ pi_w,
    float* __restrict__ V1_w, float* __restrict__ V2_w)
{
  __shared__ float r1[4][64], r2[4][64];
  const int t = threadIdx.x;
  const int d = t & 63, w = t >> 6;
  const int id = blockIdx.x;
  const int c = id & 15, h = (id >> 4) & 1, b = id >> 5;
  const int boff = b << 10;
  const float* xb = x + (size_t)(b + 32 * h) * 65536;
  float a1 = 0.f, a2 = 0.f;
#pragma unroll
  for (int i = 0; i < 16; ++i) {
    const int r = c * 64 + 4 * i + w;
    const int j = pi_w[boff + r];
    const float xv = xb[(size_t)j * 64 + d];
    a1 = fmaf(e1s_w[boff + r], xv, a1);
    a2 = fmaf(e2s_w[boff + r], xv, a2);
  }
  r1[w][d] = a1; r2[w][d] = a2;
  __syncthreads();
  if (w == 0) {
    V1_w[id * 64 + d] = r1[0][d] + r1[1][d] + r1[2][d] + r1[3][d];
    V2_w[id * 64 + d] = r2[0][d] + r2[1][d] + r2[2][d] + r2[3][d];
  }
}

// ---------------- kernel 3b: within-chunk prefix table + row emission ----------------
__global__ __launch_bounds__(256) void sweepkern(
    const float* __restrict__ x,
    const float* __restrict__ e1s_w, const float* __restrict__ e2s_w,
    const float* __restrict__ GA_w, const float* __restrict__ GB_w,
    const int* __restrict__ trk_w,
    const int* __restrict__ pi_w, const int* __restrict__ rpi_w,
    const int* __restrict__ rc_w,
    const float* __restrict__ V1_w, const float* __restrict__ V2_w,
    float* __restrict__ out)
{
  __shared__ float xs[64][64];
  __shared__ float P1[65][64], P2[65][64];
  __shared__ float es1[64], es2[64];
  __shared__ float Sg1[4][64], Sg2[4][64];
  const int t = threadIdx.x;
  const int d = t & 63, w = t >> 6;
  const int id = blockIdx.x;
  const int c = id & 15, h = (id >> 4) & 1, b = id >> 5;
  const int boff = b << 10;
  const int vbase = (b * 2 + h) << 10;

  float T1 = 0.f, ba1 = 0.f, ba2 = 0.f;
#pragma unroll
  for (int cc = 0; cc < 16; ++cc) {
    const float v1 = V1_w[vbase + cc * 64 + d];
    const float v2 = V2_w[vbase + cc * 64 + d];
    T1 += v1;
    if (cc < c) { ba1 += v1; ba2 += v2; }
  }
  if (t < 64) { es1[t] = e1s_w[boff + c * 64 + t]; es2[t] = e2s_w[boff + c * 64 + t]; }
  const float* xb = x + (size_t)(b + 32 * h) * 65536;
#pragma unroll
  for (int i = 0; i < 16; ++i) {
    const int k = 4 * i + w;
    const int j = pi_w[boff + c * 64 + k];
    xs[k][d] = xb[(size_t)j * 64 + d];
  }
  __syncthreads();
  // segmented exclusive prefix: wave w covers k in [16w, 16w+16)
  {
    float p1 = 0.f, p2 = 0.f;
#pragma unroll
    for (int kk = 0; kk < 16; ++kk) {
      const int k = 16 * w + kk;
      P1[k][d] = p1; P2[k][d] = p2;
      p1 = fmaf(es1[k], xs[k][d], p1);
      p2 = fmaf(es2[k], xs[k][d], p2);
    }
    Sg1[w][d] = p1; Sg2[w][d] = p2;
  }
  __syncthreads();
  // fixup with segment offsets; P[64] = chunk total
#pragma unroll
  for (int i = 0; i < 16; ++i) {
    const int m = 4 * i + w;
    const int seg = m >> 4;
    float o1 = 0.f, o2 = 0.f;
    for (int s2 = 0; s2 < seg; ++s2) { o1 += Sg1[s2][d]; o2 += Sg2[s2][d]; }
    P1[m][d] += o1; P2[m][d] += o2;
  }
  if (w == 0) {
    P1[64][d] = Sg1[0][d] + Sg1[1][d] + Sg1[2][d] + Sg1[3][d];
    P2[64][d] = Sg2[0][d] + Sg2[1][d] + Sg2[2][d] + Sg2[3][d];
  }
  __syncthreads();
  // emit rows of this chunk
  const int rlo = rc_w[b * 17 + c], rhi = rc_w[b * 17 + c + 1];
  float* ob = out + (size_t)(h * 32 + b) * 65536;
  for (int ri = rlo + w; ri < rhi; ri += 4) {
    const int i  = rpi_w[boff + ri];
    const float ga = GA_w[boff + i], gb = GB_w[boff + i];
    const int m = trk_w[boff + i] - c * 64;
    ob[(size_t)i * 64 + d] = ga * (T1 - ba1 - P1[m][d]) + gb * (ba2 + P2[m][d]);
  }
}

extern "C" void kernel_launch(void* const* d_in, const int* in_sizes, int n_in,
                              void* d_out, int out_size, void* d_ws, size_t ws_size,
                              hipStream_t stream) {
  const float* emb = (const float*)d_in[0];
  const float* x   = (const float*)d_in[1];
  const float* W   = (const float*)d_in[2];
  const float* a   = (const float*)d_in[3];
  float* wsf = (float*)d_ws;
  float* f1  = wsf;                  // 32768
  float* f2  = wsf + 32768;          // 32768
  float* e1s = wsf + 65536;          // 32768
  float* e2s = wsf + 98304;          // 32768
  float* GA  = wsf + 131072;         // 32768
  float* GB  = wsf + 163840;         // 32768
  float* V1  = wsf + 196608;         // 65536
  float* V2  = wsf + 262144;         // 65536
  int* pi  = (int*)(wsf + 327680);   // 32768
  int* rpi = (int*)(wsf + 360448);   // 32768
  int* trk = (int*)(wsf + 393216);   // 32768
  int* rc  = (int*)(wsf + 425984);   // 32*17
  fkern<<<512, 256, 0, stream>>>(emb, W, a, f1, f2);
  rankkern<<<32, 1024, 0, stream>>>(f1, f2, e1s, e2s, GA, GB, trk, pi, rpi, rc);
  chunkkern<<<1024, 256, 0, stream>>>(x, e1s, e2s, pi, V1, V2);
  sweepkern<<<1024, 256, 0, stream>>>(x, e1s, e2s, GA, GB, trk, pi, rpi, rc, V1, V2, (float*)d_out);
}

// Round 11
// 58.657 us; speedup vs baseline: 5.2192x; 1.0717x over previous
//
#include <hip/hip_runtime.h>

typedef float f32x4 __attribute__((ext_vector_type(4)));

#define LOG2E 1.4426950408889634f
#define ALPHA 0.2f

__device__ __forceinline__ float fexp2(float v) {
#if __has_builtin(__builtin_amdgcn_exp2f)
  return __builtin_amdgcn_exp2f(v);
#else
  return exp2f(v);
#endif
}

// ---------------- kernel 1: f1/f2 rows, pre-scaled by log2(e) (proven) ----------------
__global__ __launch_bounds__(256) void fkern(
    const float* __restrict__ emb, const float* __restrict__ W,
    const float* __restrict__ a, float* __restrict__ f1, float* __restrict__ f2)
{
  __shared__ float Ws[64 * 65];
  __shared__ float w1s[64], w2s[64];
  const int t = threadIdx.x;
#pragma unroll
  for (int i = 0; i < 16; ++i) {
    const int idx = i * 256 + t;
    Ws[(idx >> 6) * 65 + (idx & 63)] = W[idx];
  }
  __syncthreads();
  if (t < 128) {
    const int d = t & 63;
    const float* av = a + (t >> 6) * 64;
    float s = 0.f;
#pragma unroll
    for (int h = 0; h < 64; ++h) s = fmaf(Ws[d * 65 + h], av[h], s);
    if (t < 64) w1s[d] = s; else w2s[d] = s;
  }
  __syncthreads();
  const int R = blockIdx.x * 64 + (t >> 2);
  const int q = t & 3;
  const f32x4* er = (const f32x4*)(emb + (size_t)R * 64 + q * 16);
  float s1 = 0.f, s2 = 0.f;
#pragma unroll
  for (int r = 0; r < 4; ++r) {
    f32x4 v = er[r];
#pragma unroll
    for (int c = 0; c < 4; ++c) {
      s1 = fmaf(v[c], w1s[q * 16 + r * 4 + c], s1);
      s2 = fmaf(v[c], w2s[q * 16 + r * 4 + c], s2);
    }
  }
  s1 += __shfl_xor(s1, 1); s1 += __shfl_xor(s1, 2);
  s2 += __shfl_xor(s2, 1); s2 += __shfl_xor(s2, 2);
  if (q == 0) { f1[R] = s1 * LOG2E; f2[R] = s2 * LOG2E; }
}

// ---------------- kernel 2: exact sort + ranks + Z (per batch) ----------------
// Hybrid bitonic: 45 intra-wave steps via shfl_xor (no barriers), 10 cross-wave
// steps via LDS (2 barriers each).  Scans: wave shfl_up + 16-entry fixup.
__global__ __launch_bounds__(1024) void rankkern(
    const float* __restrict__ f1g, const float* __restrict__ f2g,
    float* __restrict__ e1s_w, float* __restrict__ e2s_w,
    float* __restrict__ GA_w, float* __restrict__ GB_w, int* __restrict__ trk_w,
    int* __restrict__ pi_w, int* __restrict__ rpi_w, int* __restrict__ rc_w)
{
  __shared__ unsigned long long skey[1024];
  __shared__ float sA[1024], sB[1024], sC[1024];
  __shared__ float redm[16], wt1[16], wt2[16];
  __shared__ int hist[16], hbase[17], cnt[16];
  const int t = threadIdx.x;
  const int w = t >> 6, lane = t & 63;
  const int b = blockIdx.x;
  const int boff = b << 10;

  const float f2v = f2g[boff + t];
  // wave max + cross-wave max
  float m = f2v;
#pragma unroll
  for (int off = 1; off < 64; off <<= 1) m = fmaxf(m, __shfl_xor(m, off));
  if (lane == 0) redm[w] = m;
  __syncthreads();
  float mf2 = redm[0];
#pragma unroll
  for (int i = 1; i < 16; ++i) mf2 = fmaxf(mf2, redm[i]);

  const float v = f2v - mf2;            // <= 0
  const unsigned kb = ~__builtin_bit_cast(unsigned, v);   // monotone key (proven r10)
  unsigned long long cur = ((unsigned long long)kb << 32) | (unsigned)t;

  // bitonic sort ascending on virtual index t; element kept in register
#pragma unroll
  for (int k = 2; k <= 1024; k <<= 1) {
#pragma unroll
    for (int j = k >> 1; j > 0; j >>= 1) {
      unsigned long long part;
      if (j >= 64) {
        skey[t] = cur;
        __syncthreads();
        part = skey[t ^ j];
        __syncthreads();
      } else {
        part = __shfl_xor(cur, j);
      }
      const bool up      = ((t & k) == 0);
      const bool wantmin = (((t & j) == 0) == up);
      const bool less    = (cur < part);
      cur = (wantmin == less) ? cur : part;
    }
  }

  pi_w[boff + t] = (int)(cur & 0xFFFFFFFFu);
  const float vs = __builtin_bit_cast(float, ~(unsigned)(cur >> 32));
  sA[t] = vs;
  const float e1v = fexp2(vs), e2v = fexp2(ALPHA * vs);
  e1s_w[boff + t] = e1v; e2s_w[boff + t] = e2v;

  // inclusive scans of e1,e2 over sorted order: wave shfl scan + 16-entry fixup
  float s1 = e1v, s2 = e2v;
#pragma unroll
  for (int off = 1; off < 64; off <<= 1) {
    const float n1 = __shfl_up(s1, off);
    const float n2 = __shfl_up(s2, off);
    if (lane >= off) { s1 += n1; s2 += n2; }
  }
  if (lane == 63) { wt1[w] = s1; wt2[w] = s2; }
  __syncthreads();
  float TE1 = 0.f, off1 = 0.f, off2 = 0.f;
#pragma unroll
  for (int i = 0; i < 16; ++i) {
    const float a1 = wt1[i];
    TE1 += a1;
    if (i < w) { off1 += a1; off2 += wt2[i]; }
  }
  sB[t] = s1 + off1;
  sC[t] = s2 + off2;
  __syncthreads();

  // rows: exact rank via lower_bound on sA, Z from scalar prefixes (proven r10)
  const float u   = f1g[boff + t] + mf2;
  const float tau = -u;                 // B-branch: vs < tau
  const float mL  = fmaxf(u, ALPHA * u);
  const float CA  = fexp2(u - mL);
  const float CB  = fexp2(fmaf(ALPHA, u, -mL));
  int lo = 0, hi = 1024;
  while (lo < hi) { const int mid = (lo + hi) >> 1; if (sA[mid] < tau) lo = mid + 1; else hi = mid; }
  const int ti = lo;
  const float pre1 = ti ? sB[ti - 1] : 0.f;
  const float pre2 = ti ? sC[ti - 1] : 0.f;
  const float Z = CA * (TE1 - pre1) + CB * pre2;
  GA_w[boff + t] = CA / Z;
  GB_w[boff + t] = CB / Z;
  trk_w[boff + t] = ti;
  // counting-sort rows by chunk ci = min(ti>>6, 15)
  const int ci = min(ti >> 6, 15);
  if (t < 16) { hist[t] = 0; cnt[t] = 0; }
  __syncthreads();
  atomicAdd(&hist[ci], 1);
  __syncthreads();
  if (t == 0) {
    int s = 0;
#pragma unroll
    for (int c2 = 0; c2 < 16; ++c2) { hbase[c2] = s; rc_w[b * 17 + c2] = s; s += hist[c2]; }
    rc_w[b * 17 + 16] = s;
  }
  __syncthreads();
  const int rr = hbase[ci] + atomicAdd(&cnt[ci], 1);
  rpi_w[boff + rr] = t;
}

// ---------------- kernel 3a: chunk vector sums (fixed 64-rank chunks, proven) ----------------
__global__ __launch_bounds__(256) void chunkkern(
    const float* __restrict__ x,
    const float* __restrict__ e1s_w, const float* __restrict__ e2s_w,
    const int* __restrict__ pi_w,
    float* __restrict__ V1_w, float* __restrict__ V2_w)
{
  __shared__ float r1[4][64], r2[4][64];
  const int t = threadIdx.x;
  const int d = t & 63, w = t >> 6;
  const int id = blockIdx.x;
  const int c = id & 15, h = (id >> 4) & 1, b = id >> 5;
  const int boff = b << 10;
  const float* xb = x + (size_t)(b + 32 * h) * 65536;
  float a1 = 0.f, a2 = 0.f;
#pragma unroll
  for (int i = 0; i < 16; ++i) {
    const int r = c * 64 + 4 * i + w;
    const int j = pi_w[boff + r];
    const float xv = xb[(size_t)j * 64 + d];
    a1 = fmaf(e1s_w[boff + r], xv, a1);
    a2 = fmaf(e2s_w[boff + r], xv, a2);
  }
  r1[w][d] = a1; r2[w][d] = a2;
  __syncthreads();
  if (w == 0) {
    V1_w[id * 64 + d] = r1[0][d] + r1[1][d] + r1[2][d] + r1[3][d];
    V2_w[id * 64 + d] = r2[0][d] + r2[1][d] + r2[2][d] + r2[3][d];
  }
}

// ---------------- kernel 3b: within-chunk prefix table + row emission (proven) ----------------
__global__ __launch_bounds__(256) void sweepkern(
    const float* __restrict__ x,
    const float* __restrict__ e1s_w, const float* __restrict__ e2s_w,
    const float* __restrict__ GA_w, const float* __restrict__ GB_w,
    const int* __restrict__ trk_w,
    const int* __restrict__ pi_w, const int* __restrict__ rpi_w,
    const int* __restrict__ rc_w,
    const float* __restrict__ V1_w, const float* __restrict__ V2_w,
    float* __restrict__ out)
{
  __shared__ float xs[64][64];
  __shared__ float P1[65][64], P2[65][64];
  __shared__ float es1[64], es2[64];
  __shared__ float Sg1[4][64], Sg2[4][64];
  const int t = threadIdx.x;
  const int d = t & 63, w = t >> 6;
  const int id = blockIdx.x;
  const int c = id & 15, h = (id >> 4) & 1, b = id >> 5;
  const int boff = b << 10;
  const int vbase = (b * 2 + h) << 10;

  float T1 = 0.f, ba1 = 0.f, ba2 = 0.f;
#pragma unroll
  for (int cc = 0; cc < 16; ++cc) {
    const float v1 = V1_w[vbase + cc * 64 + d];
    const float v2 = V2_w[vbase + cc * 64 + d];
    T1 += v1;
    if (cc < c) { ba1 += v1; ba2 += v2; }
  }
  if (t < 64) { es1[t] = e1s_w[boff + c * 64 + t]; es2[t] = e2s_w[boff + c * 64 + t]; }
  const float* xb = x + (size_t)(b + 32 * h) * 65536;
#pragma unroll
  for (int i = 0; i < 16; ++i) {
    const int k = 4 * i + w;
    const int j = pi_w[boff + c * 64 + k];
    xs[k][d] = xb[(size_t)j * 64 + d];
  }
  __syncthreads();
  {
    float p1 = 0.f, p2 = 0.f;
#pragma unroll
    for (int kk = 0; kk < 16; ++kk) {
      const int k = 16 * w + kk;
      P1[k][d] = p1; P2[k][d] = p2;
      p1 = fmaf(es1[k], xs[k][d], p1);
      p2 = fmaf(es2[k], xs[k][d], p2);
    }
    Sg1[w][d] = p1; Sg2[w][d] = p2;
  }
  __syncthreads();
#pragma unroll
  for (int i = 0; i < 16; ++i) {
    const int m = 4 * i + w;
    const int seg = m >> 4;
    float o1 = 0.f, o2 = 0.f;
    for (int s2 = 0; s2 < seg; ++s2) { o1 += Sg1[s2][d]; o2 += Sg2[s2][d]; }
    P1[m][d] += o1; P2[m][d] += o2;
  }
  if (w == 0) {
    P1[64][d] = Sg1[0][d] + Sg1[1][d] + Sg1[2][d] + Sg1[3][d];
    P2[64][d] = Sg2[0][d] + Sg2[1][d] + Sg2[2][d] + Sg2[3][d];
  }
  __syncthreads();
  const int rlo = rc_w[b * 17 + c], rhi = rc_w[b * 17 + c + 1];
  float* ob = out + (size_t)(h * 32 + b) * 65536;
  for (int ri = rlo + w; ri < rhi; ri += 4) {
    const int i  = rpi_w[boff + ri];
    const float ga = GA_w[boff + i], gb = GB_w[boff + i];
    const int m = trk_w[boff + i] - c * 64;
    ob[(size_t)i * 64 + d] = ga * (T1 - ba1 - P1[m][d]) + gb * (ba2 + P2[m][d]);
  }
}

extern "C" void kernel_launch(void* const* d_in, const int* in_sizes, int n_in,
                              void* d_out, int out_size, void* d_ws, size_t ws_size,
                              hipStream_t stream) {
  const float* emb = (const float*)d_in[0];
  const float* x   = (const float*)d_in[1];
  const float* W   = (const float*)d_in[2];
  const float* a   = (const float*)d_in[3];
  float* wsf = (float*)d_ws;
  float* f1  = wsf;                  // 32768
  float* f2  = wsf + 32768;          // 32768
  float* e1s = wsf + 65536;          // 32768
  float* e2s = wsf + 98304;          // 32768
  float* GA  = wsf + 131072;         // 32768
  float* GB  = wsf + 163840;         // 32768
  float* V1  = wsf + 196608;         // 65536
  float* V2  = wsf + 262144;         // 65536
  int* pi  = (int*)(wsf + 327680);   // 32768
  int* rpi = (int*)(wsf + 360448);   // 32768
  int* trk = (int*)(wsf + 393216);   // 32768
  int* rc  = (int*)(wsf + 425984);   // 32*17
  fkern<<<512, 256, 0, stream>>>(emb, W, a, f1, f2);
  rankkern<<<32, 1024, 0, stream>>>(f1, f2, e1s, e2s, GA, GB, trk, pi, rpi, rc);
  chunkkern<<<1024, 256, 0, stream>>>(x, e1s, e2s, pi, V1, V2);
  sweepkern<<<1024, 256, 0, stream>>>(x, e1s, e2s, GA, GB, trk, pi, rpi, rc, V1, V2, (float*)d_out);
}